// Round 5
// baseline (153.779 us; speedup 1.0000x reference)
//
#include <hip/hip_runtime.h>
#include <math.h>

#define KQ   32768
#define CC   100
#define BB   1024
#define DD   128
#define NTOT (BB + KQ)        // 33792
#define CB_CENT 1056
#define NCB  1060             // 32-row blocks in X2
#define NHIST 33              // histogram partial blocks
#define NCG2 132              // branch-2 col groups (8 cb each)
#define CG_SUP 141            // sup group id (after 9 branch-1 groups)
#define NSL  141              // partial-sum slices (132 b2 + 9 b1)

#define INV_T  14.285714285714286f
#define K2E    20.609929f     // INV_T * log2(e)
#define ALPHA  0.05f
#define EPSV   1e-12f

typedef __attribute__((ext_vector_type(8)))  short          short8;
typedef __attribute__((ext_vector_type(8)))  unsigned short ushort8;
typedef __attribute__((ext_vector_type(16))) float          float16;

__device__ __forceinline__ unsigned short f2bf_rne(float f) {
    unsigned int u = __float_as_uint(f);
    return (unsigned short)((u + 0x7FFFu + ((u >> 16) & 1u)) >> 16);
}

// X2 layout per 32-row block cb (8192 B): [ks 0..7][lane 0..63][16 B]
// element (row r, k): cb=r>>5, ks=k>>4, lane=(r&31)+32*((k>>3)&1), j=k&7
// == 32x32x16 MFMA A/B operand layout (verified R2-R15).
// HARD RULES: no device-scope fences/tickets in hot kernel (R13);
// never plain-store into a cross-block atomic accumulation target (R14);
// gemm_k VGPR real need ~185 with 64-row waves: keep launch cap >= 256
// (R1 post-mortem: cap 64 -> 126 MB scratch spill, 1.3x regression).
// R0-R4 post-mortem: gemm wall 56us invariant across 4 structures; counters
// fit effective clock ~600MHz (DVFS floor, reps 2ms apart) with ~35% VALU
// issue + ~50% LDS-pipe busy -> R5 halves LDS/B traffic per output via
// 64-row waves (two A strips share every B read).

// ---------------- prep: convert+tile (1 cb/block) + partial histograms ----------------
__global__ __launch_bounds__(256) void prep_k(const float* __restrict__ feats,
                                              const float* __restrict__ centers,
                                              const int* __restrict__ labels,
                                              unsigned short* __restrict__ X2,
                                              int* __restrict__ cntP,
                                              int* __restrict__ cntB) {
    const int b = blockIdx.x, t = threadIdx.x;
    if (b >= NCB) {  // histogram partials: each block owns its own 128-int slice
        const int h = b - NCB;
        __shared__ int hA[CC], hB[CC];
        if (t < CC) { hA[t] = 0; hB[t] = 0; }
        __syncthreads();
        const int base = h * 1024;
#pragma unroll
        for (int q = 0; q < 4; ++q) {
            int l = labels[base + q * 256 + t];
            atomicAdd(&hA[l], 1);
            if (h == 0) atomicAdd(&hB[l], 1);   // batch rows are exactly block 0's range
        }
        __syncthreads();
        if (t < 128) {
            cntP[h * 128 + t] = (t < CC) ? hA[t] : 0;
            if (h == 0) cntB[t] = (t < CC) ? hB[t] : 0;
        }
        return;
    }
    __shared__ unsigned short sm[8 * 66 * 8];   // stride-66 slots
    const int cb = b;
    const int rl = t >> 3, c8 = t & 7;
    const int r = cb * 32 + rl;
    const float* src;
    if (r < NTOT)            src = &feats[(size_t)r * DD];
    else if (r < NTOT + CC)  src = &centers[(size_t)(r - NTOT) * DD];
    else                     src = nullptr;
#pragma unroll
    for (int s = 0; s < 2; ++s) {
        const int c8p = c8 + 8 * s;
        float v[8];
        if (src) {
            const float4* p = (const float4*)(src + c8p * 8);
            float4 q0 = p[0], q1 = p[1];
            v[0]=q0.x; v[1]=q0.y; v[2]=q0.z; v[3]=q0.w;
            v[4]=q1.x; v[5]=q1.y; v[6]=q1.z; v[7]=q1.w;
        } else {
#pragma unroll
            for (int j = 0; j < 8; ++j) v[j] = 0.f;
        }
        ushort8 H;
#pragma unroll
        for (int m = 0; m < 8; ++m) H[m] = f2bf_rne(v[m]);
        const int ks = c8p >> 1, lh = c8p & 1;
        *(ushort8*)&sm[(ks * 66 + rl + 32 * lh) * 8] = H;
    }
    __syncthreads();
    ushort8* dst = (ushort8*)((char*)X2 + (size_t)cb * 8192);
#pragma unroll
    for (int j = 0; j < 2; ++j) {
        const int idx = j * 256 + t;
        const int ks = idx >> 6, ln2 = idx & 63;
        dst[idx] = *(const ushort8*)&sm[(ks * 66 + ln2) * 8];
    }
}

// ---------------- tables: one tiny block; sums hist partials, emits weight tables ------
__global__ __launch_bounds__(128) void tables_k(
    const int* __restrict__ cntP, const int* __restrict__ cntB,
    float2* __restrict__ wA, float2* __restrict__ w1, float2* __restrict__ wS,
    float* __restrict__ cAf, int* __restrict__ cBi) {
    const int t = threadIdx.x;   // 0..127
    int s = 0;
#pragma unroll
    for (int h = 0; h < NHIST; ++h) s += cntP[h * 128 + t];
    float cf = (float)s;
    float rn = (s > 0) ? __builtin_amdgcn_rcpf(cf) : 0.f;
    float dr = (s > 0) ? (__builtin_amdgcn_rcpf(cf - ALPHA) - rn) : 0.f;
    wA[t] = make_float2(rn, dr);
    wS[t] = make_float2(__builtin_amdgcn_rcpf(cf),
                        __builtin_amdgcn_rcpf(fmaxf(cf - 1.f, 1.f)));
    int sb = cntB[t];
    float c1 = (float)(sb + 1);
    float r1 = __builtin_amdgcn_rcpf(c1);
    w1[t] = make_float2(r1, __builtin_amdgcn_rcpf(fmaxf(c1 - 1.f, 1.f)) - r1);
    cAf[t] = cf;
    cBi[t] = sb;
}

// ---------------- epilogue for one 32x32 tile ----------------
__device__ __forceinline__ void epi_tile(
    const float16& acc, int cb, int lc, float rn, float drm, bool checkDiag,
    int half, int ln, int growbase, const int* rlab, float* sS, float* sN)
{
    const int ccol = cb * 32 + ln;
#pragma unroll
    for (int reg = 0; reg < 16; ++reg) {
        int ro = (reg & 3) + 8 * (reg >> 2) + 4 * half;
        float a  = acc[reg];
        float mf = (lc == rlab[reg]) ? 1.f : 0.f;
        float wgt = fmaf(mf, drm, rn);
        if (checkDiag) {                 // wave-uniform
            bool d = (ccol == growbase + ro);
            wgt = d ? 0.f : wgt;
            mf  = d ? 0.f : mf;
        }
        float e = exp2f(fmaf(a, K2E, -K2E));
        sS[reg] = fmaf(e, wgt, sS[reg]);
        sN[reg] = fmaf(mf, a, sN[reg]);  // un-scaled dot; *INV_T at finalize
    }
}

// ---------------- fused GEMM (b2 + b1) + sup-sums; 64-row waves, LDS dbuf --------------
// grid 576 = 18 chunk * 4 rgrp * 8 xcd; cg = chunk*8 + xcd.
// cg<132: branch2 (8 cb). 132..140: branch1 (4 cb). 141: sup sums. 142/143: idle.
// Each wave owns TWO 32-row A strips (rb0, rb1); every B-tile LDS read feeds two
// MFMA chains -> LDS reads / barriers / A-loads per output element halve vs R4.
__global__ __launch_bounds__(256, 2) void gemm_k(
    const unsigned short* __restrict__ X2, const int* __restrict__ labels,
    const float2* __restrict__ wA, const float2* __restrict__ w1,
    const float2* __restrict__ wS, const float* __restrict__ sup,
    float* __restrict__ pS, float* __restrict__ pN,
    float* __restrict__ supS, float* __restrict__ supLi) {
    const int b = blockIdx.x;
    const int xcd = b & 7, rgrp = (b >> 3) & 3, chunk = b >> 5;
    const int cg = chunk * 8 + xcd;
    if (cg > CG_SUP) return;

    const int tid = threadIdx.x;
    const int w = tid >> 6, lane = tid & 63;
    const int half = lane >> 5, ln = lane & 31;
    const char* Xb = (const char*)X2;

    if (cg == CG_SUP) {  // sup-logits exp-sums: wave owns 64 rows
        const int c0 = lane, c1 = lane + 64;
        float2 t0 = wS[c0];
        float rA0 = t0.x, rAm0 = t0.y;
        float rA1 = 0.f, rAm1 = 0.f;
        if (lane < 36) { float2 t1v = wS[c1]; rA1 = t1v.x; rAm1 = t1v.y; }
        const int rbase = rgrp * 256 + w * 64;
        for (int rr = 0; rr < 64; ++rr) {
            int row = rbase + rr;
            int li = labels[row];
            const float* srow = &sup[(size_t)row * CC];
            float v0 = srow[c0];
            float s = __expf(v0 - INV_T) * ((c0 == li) ? rAm0 : rA0);
            float liv = (c0 == li) ? v0 : 0.f;
            if (lane < 36) {
                float v1 = srow[c1];
                s += __expf(v1 - INV_T) * ((c1 == li) ? rAm1 : rA1);
                liv += (c1 == li) ? v1 : 0.f;
            }
#pragma unroll
            for (int off = 1; off < 64; off <<= 1) {
                s += __shfl_xor(s, off, 64);
                liv += __shfl_xor(liv, off, 64);
            }
            if (lane == 0) { supS[row] = s; supLi[row] = liv; }
        }
        return;
    }

    __shared__ char sm[2 * 8192];       // double-buffered B tile (MFMA operand order)
    __shared__ float2 wT[128];          // LDS copy of the relevant weight table

    const bool isB2 = (cg < NCG2);
    const int t1 = cg - NCG2;
    const bool isBatch = isB2 || (t1 < 8);
    const int NIT = isB2 ? 8 : 4;
    const int cb0 = isB2 ? cg * 8 : (t1 < 8 ? t1 * 4 : CB_CENT);

    if (tid < 128) wT[tid] = isB2 ? wA[tid] : w1[tid];

    // two 32-row A strips per wave
    const int rb0 = rgrp * 8 + w * 2, rb1 = rb0 + 1;
    const int growb0 = rb0 * 32, growb1 = rb1 * 32;

    // ---- hoisted per-tile column labels (independent global gathers) ----
    int lcv[8];
#pragma unroll
    for (int i = 0; i < 8; ++i) {
        if (i < NIT) {
            const int cb = cb0 + i;
            if (isBatch) {
                lcv[i] = labels[cb * 32 + ln];
            } else {
                int q = cb * 32 + ln - NTOT;
                lcv[i] = (q < CC) ? q : -1;
            }
        } else lcv[i] = -1;
    }

    short8 Ah0[8], Ah1[8];
    {
        size_t a0 = (size_t)rb0 * 8192 + (size_t)lane * 16;
        size_t a1 = (size_t)rb1 * 8192 + (size_t)lane * 16;
#pragma unroll
        for (int ks = 0; ks < 8; ++ks) {
            Ah0[ks] = *(const short8*)(Xb + a0 + (size_t)ks * 1024);
            Ah1[ks] = *(const short8*)(Xb + a1 + (size_t)ks * 1024);
        }
    }
    int rlab0[16], rlab1[16];
#pragma unroll
    for (int reg = 0; reg < 16; ++reg) {
        int ro = (reg & 3) + 8 * (reg >> 2) + 4 * half;
        rlab0[reg] = labels[growb0 + ro];
        rlab1[reg] = labels[growb1 + ro];
    }

    float sS0[16], sN0[16], sS1[16], sN1[16];
#pragma unroll
    for (int reg = 0; reg < 16; ++reg) {
        sS0[reg] = 0.f; sN0[reg] = 0.f; sS1[reg] = 0.f; sN1[reg] = 0.f;
    }

    // per-wave staging offsets: wave w owns ks-slices 2w, 2w+1 (1 KB each)
    const int soff = (w * 2) * 1024 + lane * 16;

    // prologue: stage cb0 into buffer 0
    {
        const char* src = Xb + (size_t)cb0 * 8192 + soff;
        short8 s0 = *(const short8*)src;
        short8 s1 = *(const short8*)(src + 1024);
        *(short8*)&sm[soff] = s0;
        *(short8*)&sm[soff + 1024] = s1;
    }
    __syncthreads();

    for (int i = 0; i < NIT; ++i) {
        const int cb = cb0 + i;
        // issue next tile's global loads early (latency hides under compute)
        short8 st0, st1;
        const bool more = (i + 1 < NIT);
        if (more) {
            const char* src = Xb + (size_t)(cb + 1) * 8192 + soff;
            st0 = *(const short8*)src;
            st1 = *(const short8*)(src + 1024);
        }
        // per-tile weights from LDS table
        int lc = lcv[i];
        float2 wv = wT[(lc >= 0) ? lc : 0];
        float rn  = (lc >= 0) ? wv.x : 0.f;
        float drm = (lc >= 0) ? wv.y : 0.f;
        // compute both strips from one pass over the LDS B tile
        const char* Bp = &sm[(i & 1) * 8192 + lane * 16];
        float16 a0, a1;
#pragma unroll
        for (int reg = 0; reg < 16; ++reg) { a0[reg] = 0.f; a1[reg] = 0.f; }
#pragma unroll
        for (int ks = 0; ks < 8; ++ks) {
            short8 Bf = *(const short8*)(Bp + ks * 1024);
            a0 = __builtin_amdgcn_mfma_f32_32x32x16_bf16(Ah0[ks], Bf, a0, 0, 0, 0);
            a1 = __builtin_amdgcn_mfma_f32_32x32x16_bf16(Ah1[ks], Bf, a1, 0, 0, 0);
        }
        epi_tile(a0, cb, lc, rn, drm, isBatch && (cb == rb0),
                 half, ln, growb0, rlab0, sS0, sN0);
        epi_tile(a1, cb, lc, rn, drm, isBatch && (cb == rb1),
                 half, ln, growb1, rlab1, sS1, sN1);
        // commit staged tile to the other buffer, then one barrier
        if (more) {
            char* d = &sm[((i + 1) & 1) * 8192 + soff];
            *(short8*)d = st0;
            *(short8*)(d + 1024) = st1;
        }
        __syncthreads();
    }

    const int slice = isB2 ? cg : (NCG2 + t1);
#pragma unroll
    for (int reg = 0; reg < 16; ++reg) {
        float av0 = sS0[reg], c0v = sN0[reg];
        float av1 = sS1[reg], c1v = sN1[reg];
#pragma unroll
        for (int off = 1; off < 32; off <<= 1) {
            av0 += __shfl_xor(av0, off, 64);
            c0v += __shfl_xor(c0v, off, 64);
            av1 += __shfl_xor(av1, off, 64);
            c1v += __shfl_xor(c1v, off, 64);
        }
        if (ln == 0) {
            int ro = (reg & 3) + 8 * (reg >> 2) + 4 * half;
            pS[(size_t)slice * BB + growb0 + ro] = av0;
            pN[(size_t)slice * BB + growb0 + ro] = c0v;
            pS[(size_t)slice * BB + growb1 + ro] = av1;
            pN[(size_t)slice * BB + growb1 + ro] = c1v;
        }
    }
}

// ---------------- reduce: 128 blocks; 32 threads/row sum the 141 slices + loss math ----
__global__ __launch_bounds__(256) void reduce_k(
    const int* __restrict__ labels,
    const float* __restrict__ cAf, const int* __restrict__ cBi,
    const float* __restrict__ pS, const float* __restrict__ pN,
    const float* __restrict__ supS, const float* __restrict__ supLi,
    float* __restrict__ partial) {
    const int g = blockIdx.x, t = threadIdx.x;
    const int rl = t >> 5, j = t & 31;        // 8 rows/block, 32 lanes/row
    const int row = g * 8 + rl;
    float S2 = 0.f, N2 = 0.f, S1 = 0.f, N1v = 0.f;
    for (int c = j; c < NCG2; c += 32) {
        S2 += pS[(size_t)c * BB + row];
        N2 += pN[(size_t)c * BB + row];
    }
    if (NCG2 + j < NSL) {
        S1  += pS[(size_t)(NCG2 + j) * BB + row];
        N1v += pN[(size_t)(NCG2 + j) * BB + row];
    }
#pragma unroll
    for (int off = 1; off < 32; off <<= 1) {
        S2 += __shfl_xor(S2, off, 64);  N2  += __shfl_xor(N2, off, 64);
        S1 += __shfl_xor(S1, off, 64);  N1v += __shfl_xor(N1v, off, 64);
    }
    float s = 0.f;
    if (j == 0) {
        int li = labels[row];
        S2 += supS[row];
        N2 *= INV_T; N1v *= INV_T;
        float sli = supLi[row];
        float cA = cAf[li];
        float msum2 = fmaf(ALPHA, cA - 1.f, 1.f);
        float loss2 = -(fmaf(ALPHA, N2, sli) / msum2 - INV_T - logf(S2 + EPSV));
        float loss1 = -(N1v / (float)cBi[li] - INV_T - logf(S1 + EPSV));
        s = loss1 + loss2;
    }
#pragma unroll
    for (int off = 1; off < 64; off <<= 1) s += __shfl_xor(s, off, 64);
    __shared__ float buf[4];
    if ((t & 63) == 0) buf[t >> 6] = s;
    __syncthreads();
    if (t == 0) partial[g] = (buf[0] + buf[1]) + (buf[2] + buf[3]);
}

// ---------------- final: one wave sums 128 block partials ----------------
__global__ __launch_bounds__(64) void final_k(const float* __restrict__ partial,
                                              float* __restrict__ out) {
    const int t = threadIdx.x;
    float s = partial[t] + partial[t + 64];
#pragma unroll
    for (int off = 1; off < 64; off <<= 1) s += __shfl_xor(s, off, 64);
    if (t == 0) out[0] = s / (float)BB;   // single writer, plain store
}

extern "C" void kernel_launch(void* const* d_in, const int* in_sizes, int n_in,
                              void* d_out, int out_size, void* d_ws, size_t ws_size,
                              hipStream_t stream) {
    const float* feats   = (const float*)d_in[0];
    const float* sup     = (const float*)d_in[1];
    const float* centers = (const float*)d_in[2];
    const int*   labels  = (const int*)d_in[3];
    float* out = (float*)d_out;
    char*  wsb = (char*)d_ws;

    const size_t X2_BYTES = (size_t)NCB * 8192;         // 8,683,520
    unsigned short* X2 = (unsigned short*)wsb;
    char* base2 = wsb + X2_BYTES;
    int* cntP = (int*)base2;                            // 33*128 ints
    int* cntB = cntP + NHIST * 128;                     // 128 ints
    float2* wA = (float2*)(cntB + 128);                 // 128 float2 (8B-aligned)
    float2* w1 = wA + 128;                              // 128 float2
    float2* wS = w1 + 128;                              // 128 float2
    float*  cAf = (float*)(wS + 128);                   // 128 floats
    int*    cBi = (int*)(cAf + 128);                    // 128 ints
    float* pS = (float*)(cBi + 128);                    // 141*1024
    float* pN = pS + (size_t)NSL * BB;                  // 141*1024
    float* supS  = pN + (size_t)NSL * BB;               // 1024
    float* supLi = supS + BB;                           // 1024
    float* partial = supLi + BB;                        // 128

    // 5 nodes; every workspace word written before read (stream-ordered)
    prep_k<<<NCB + NHIST, 256, 0, stream>>>(feats, centers, labels, X2, cntP, cntB);
    tables_k<<<1, 128, 0, stream>>>(cntP, cntB, wA, w1, wS, cAf, cBi);
    gemm_k<<<18 * 32, 256, 0, stream>>>(X2, labels, wA, w1, wS, sup,
                                        pS, pN, supS, supLi);
    reduce_k<<<128, 256, 0, stream>>>(labels, cAf, cBi, pS, pN, supS, supLi, partial);
    final_k<<<1, 64, 0, stream>>>(partial, out);
}

// Round 6
// 121.133 us; speedup vs baseline: 1.2695x; 1.2695x over previous
//
#include <hip/hip_runtime.h>
#include <math.h>

#define KQ   32768
#define CC   100
#define BB   1024
#define DD   128
#define NTOT (BB + KQ)        // 33792
#define CB_CENT 1056
#define NCB  1060             // 32-row blocks in X2
#define NHIST 33              // histogram partial blocks
#define NCG2 132              // branch-2 col groups (8 cb each)
#define CG_SUP 141            // sup group id (after 9 branch-1 groups)
#define NSL  141              // partial-sum slices (132 b2 + 9 b1)

#define INV_T  14.285714285714286f
#define K2E    20.609929f     // INV_T * log2(e)
#define ALPHA  0.05f
#define EPSV   1e-12f

typedef __attribute__((ext_vector_type(8)))  short          short8;
typedef __attribute__((ext_vector_type(8)))  unsigned short ushort8;
typedef __attribute__((ext_vector_type(16))) float          float16;

__device__ __forceinline__ unsigned short f2bf_rne(float f) {
    unsigned int u = __float_as_uint(f);
    return (unsigned short)((u + 0x7FFFu + ((u >> 16) & 1u)) >> 16);
}

// async global->LDS, 16B per lane: LDS dest = wave-uniform base + lane*16,
// global src is per-lane. Completion tracked by vmcnt; __syncthreads drains.
__device__ __forceinline__ void glds16(const void* g, void* l) {
    __builtin_amdgcn_global_load_lds(
        (const __attribute__((address_space(1))) void*)g,
        (__attribute__((address_space(3))) void*)l, 16, 0, 0);
}

// X2 layout per 32-row block cb (8192 B): [ks 0..7][lane 0..63][16 B]
// element (row r, k): cb=r>>5, ks=k>>4, lane=(r&31)+32*((k>>3)&1), j=k&7
// == 32x32x16 MFMA A/B operand layout (verified R2-R15).
// HARD RULES: no device-scope fences/tickets in hot kernel (R13);
// never plain-store into a cross-block atomic accumulation target (R14);
// gemm_k register demand must stay <= ~128 at 256-thread blocks:
//   R1: cap 64 -> 126 MB scratch spill, 1.3x regression.
//   R5: 2-A-strip variant needs ~185 -> allocator clamps at 128 and spills
//       (FETCH+WRITE ballooned, gemm 56->90us). Single 32-row strip only.
// R0-R4: gemm wall 56us invariant across 4 structures; counters fit
// effective clock ~600MHz (DVFS floor) with ~50% LDS-pipe + ~34% VALU.
// R6: cut LDS-issue cycles via global_load_lds staging; fold tables_k away.

// ---------------- prep: convert+tile (1 cb/block) + partial histograms ----------------
__global__ __launch_bounds__(256) void prep_k(const float* __restrict__ feats,
                                              const float* __restrict__ centers,
                                              const int* __restrict__ labels,
                                              unsigned short* __restrict__ X2,
                                              int* __restrict__ cntP,
                                              int* __restrict__ cntB) {
    const int b = blockIdx.x, t = threadIdx.x;
    if (b >= NCB) {  // histogram partials: each block owns its own 128-int slice
        const int h = b - NCB;
        __shared__ int hA[CC], hB[CC];
        if (t < CC) { hA[t] = 0; hB[t] = 0; }
        __syncthreads();
        const int base = h * 1024;
#pragma unroll
        for (int q = 0; q < 4; ++q) {
            int l = labels[base + q * 256 + t];
            atomicAdd(&hA[l], 1);
            if (h == 0) atomicAdd(&hB[l], 1);   // batch rows are exactly block 0's range
        }
        __syncthreads();
        if (t < 128) {
            cntP[h * 128 + t] = (t < CC) ? hA[t] : 0;
            if (h == 0) cntB[t] = (t < CC) ? hB[t] : 0;
        }
        return;
    }
    __shared__ unsigned short sm[8 * 66 * 8];   // stride-66 slots
    const int cb = b;
    const int rl = t >> 3, c8 = t & 7;
    const int r = cb * 32 + rl;
    const float* src;
    if (r < NTOT)            src = &feats[(size_t)r * DD];
    else if (r < NTOT + CC)  src = &centers[(size_t)(r - NTOT) * DD];
    else                     src = nullptr;
#pragma unroll
    for (int s = 0; s < 2; ++s) {
        const int c8p = c8 + 8 * s;
        float v[8];
        if (src) {
            const float4* p = (const float4*)(src + c8p * 8);
            float4 q0 = p[0], q1 = p[1];
            v[0]=q0.x; v[1]=q0.y; v[2]=q0.z; v[3]=q0.w;
            v[4]=q1.x; v[5]=q1.y; v[6]=q1.z; v[7]=q1.w;
        } else {
#pragma unroll
            for (int j = 0; j < 8; ++j) v[j] = 0.f;
        }
        ushort8 H;
#pragma unroll
        for (int m = 0; m < 8; ++m) H[m] = f2bf_rne(v[m]);
        const int ks = c8p >> 1, lh = c8p & 1;
        *(ushort8*)&sm[(ks * 66 + rl + 32 * lh) * 8] = H;
    }
    __syncthreads();
    ushort8* dst = (ushort8*)((char*)X2 + (size_t)cb * 8192);
#pragma unroll
    for (int j = 0; j < 2; ++j) {
        const int idx = j * 256 + t;
        const int ks = idx >> 6, ln2 = idx & 63;
        dst[idx] = *(const ushort8*)&sm[(ks * 66 + ln2) * 8];
    }
}

// ---------------- epilogue for one 32x32 tile ----------------
__device__ __forceinline__ void epi_tile(
    const float16& acc, int cb, int lc, float rn, float drm, bool checkDiag,
    int half, int ln, int growbase, const int* rlab, float* sS, float* sN)
{
    const int ccol = cb * 32 + ln;
#pragma unroll
    for (int reg = 0; reg < 16; ++reg) {
        int ro = (reg & 3) + 8 * (reg >> 2) + 4 * half;
        float a  = acc[reg];
        float mf = (lc == rlab[reg]) ? 1.f : 0.f;
        float wgt = fmaf(mf, drm, rn);
        if (checkDiag) {                 // wave-uniform
            bool d = (ccol == growbase + ro);
            wgt = d ? 0.f : wgt;
            mf  = d ? 0.f : mf;
        }
        float e = exp2f(fmaf(a, K2E, -K2E));
        sS[reg] = fmaf(e, wgt, sS[reg]);
        sN[reg] = fmaf(mf, a, sN[reg]);  // un-scaled dot; *INV_T at finalize
    }
}

// ---------------- fused GEMM (b2 + b1) + sup-sums; 4-wave, glds double-buffer ----------
// grid 1152 = 18 chunk * 8 rgrp * 8 xcd; cg = chunk*8 + xcd.
// cg<132: branch2 (8 cb). 132..140: branch1 (4 cb). 141: sup sums. 142/143: idle.
// Weight tables built in-block from histogram partials (tables_k folded away, R0-style).
// B-tile staging via global_load_lds (no VGPR round-trip, no ds_write issue cycles);
// double-buffered, one barrier per tile (drains vmcnt for the staged buffer).
__global__ __launch_bounds__(256, 2) void gemm_k(
    const unsigned short* __restrict__ X2, const int* __restrict__ labels,
    const int* __restrict__ cntP, const int* __restrict__ cntB,
    const float* __restrict__ sup,
    float* __restrict__ pS, float* __restrict__ pN,
    float* __restrict__ supS, float* __restrict__ supLi) {
    const int b = blockIdx.x;
    const int xcd = b & 7, rgrp = (b >> 3) & 7, chunk = b >> 6;
    const int cg = chunk * 8 + xcd;
    if (cg > CG_SUP) return;

    const int tid = threadIdx.x;
    const int w = tid >> 6, lane = tid & 63;
    const int half = lane >> 5, ln = lane & 31;
    const int rb = rgrp * 4 + w;
    const char* Xb = (const char*)X2;

    if (cg == CG_SUP) {  // sup-logits exp-sums: wave owns rows rb*32..rb*32+31
        const int c0 = lane, c1 = lane + 64;
        int s0 = 0, s1 = 0;
#pragma unroll
        for (int h = 0; h < NHIST; ++h) {
            s0 += cntP[h * 128 + c0];
            s1 += cntP[h * 128 + c1];
        }
        float n0 = (float)s0;
        float rA0 = __builtin_amdgcn_rcpf(n0);
        float rAm0 = __builtin_amdgcn_rcpf(fmaxf(n0 - 1.f, 1.f));
        float rA1 = 0.f, rAm1 = 0.f;
        if (lane < 36) {
            float n1 = (float)s1;
            rA1 = __builtin_amdgcn_rcpf(n1);
            rAm1 = __builtin_amdgcn_rcpf(fmaxf(n1 - 1.f, 1.f));
        }
        for (int rr = 0; rr < 32; ++rr) {
            int row = rb * 32 + rr;
            int li = labels[row];
            const float* srow = &sup[(size_t)row * CC];
            float v0 = srow[c0];
            float s = __expf(v0 - INV_T) * ((c0 == li) ? rAm0 : rA0);
            float liv = (c0 == li) ? v0 : 0.f;
            if (lane < 36) {
                float v1 = srow[c1];
                s += __expf(v1 - INV_T) * ((c1 == li) ? rAm1 : rA1);
                liv += (c1 == li) ? v1 : 0.f;
            }
#pragma unroll
            for (int off = 1; off < 64; off <<= 1) {
                s += __shfl_xor(s, off, 64);
                liv += __shfl_xor(liv, off, 64);
            }
            if (lane == 0) { supS[row] = s; supLi[row] = liv; }
        }
        return;
    }

    __shared__ char sm[2 * 8192];       // double-buffered B tile (MFMA operand order)
    __shared__ float2 wT[128];          // in-block weight table

    const bool isB2 = (cg < NCG2);
    const int t1 = cg - NCG2;
    const bool isBatch = isB2 || (t1 < 8);
    const int NIT = isB2 ? 8 : 4;
    const int cb0 = isB2 ? cg * 8 : (t1 < 8 ? t1 * 4 : CB_CENT);

    // in-block weight table from histogram partials (exact tables_k expressions)
    if (tid < 128) {
        int s = 0;
#pragma unroll
        for (int h = 0; h < NHIST; ++h) s += cntP[h * 128 + tid];
        float2 wv;
        if (isB2) {
            float cf = (float)s;
            float rn = (s > 0) ? __builtin_amdgcn_rcpf(cf) : 0.f;
            wv = make_float2(rn, (s > 0) ? (__builtin_amdgcn_rcpf(cf - ALPHA) - rn) : 0.f);
        } else {
            float c1 = (float)(cntB[tid] + 1);
            float r1 = __builtin_amdgcn_rcpf(c1);
            wv = make_float2(r1, __builtin_amdgcn_rcpf(fmaxf(c1 - 1.f, 1.f)) - r1);
        }
        wT[tid] = wv;
    }

    // prologue: async-stage cb0 into buffer 0 (wave w owns 2 KB slice)
    const int wbase = w * 2048;
    {
        const char* src = Xb + (size_t)cb0 * 8192 + wbase + lane * 16;
        glds16(src, &sm[wbase]);
        glds16(src + 1024, &sm[wbase + 1024]);
    }

    // ---- hoisted per-tile column labels (independent global gathers) ----
    int lcv[8];
#pragma unroll
    for (int i = 0; i < 8; ++i) {
        if (i < NIT) {
            const int cb = cb0 + i;
            if (isBatch) {
                lcv[i] = labels[cb * 32 + ln];
            } else {
                int q = cb * 32 + ln - NTOT;
                lcv[i] = (q < CC) ? q : -1;
            }
        } else lcv[i] = -1;
    }

    const int growbase = rb * 32;
    short8 Ah[8];
    {
        size_t abase = (size_t)rb * 8192 + (size_t)lane * 16;
#pragma unroll
        for (int ks = 0; ks < 8; ++ks)
            Ah[ks] = *(const short8*)(Xb + abase + (size_t)ks * 1024);
    }
    int rlab[16];
#pragma unroll
    for (int reg = 0; reg < 16; ++reg) {
        int ro = (reg & 3) + 8 * (reg >> 2) + 4 * half;
        rlab[reg] = labels[growbase + ro];
    }

    __syncthreads();   // wT visible + buffer-0 staging drained (vmcnt)

    // ---- hoisted per-tile weights from LDS table ----
    float rnv[8], drv[8];
#pragma unroll
    for (int i = 0; i < 8; ++i) {
        if (i < NIT) {
            int lc = lcv[i];
            float2 wv = wT[(lc >= 0) ? lc : 0];
            rnv[i] = (lc >= 0) ? wv.x : 0.f;
            drv[i] = (lc >= 0) ? wv.y : 0.f;
        } else { rnv[i] = 0.f; drv[i] = 0.f; }
    }

    float sS[16], sN[16];
#pragma unroll
    for (int reg = 0; reg < 16; ++reg) { sS[reg] = 0.f; sN[reg] = 0.f; }

    for (int i = 0; i < NIT; ++i) {
        const int cb = cb0 + i;
        const bool more = (i + 1 < NIT);
        // async-issue next tile's staging into the other buffer
        if (more) {
            const char* src = Xb + (size_t)(cb + 1) * 8192 + wbase + lane * 16;
            char* dl = &sm[((i + 1) & 1) * 8192 + wbase];
            glds16(src, dl);
            glds16(src + 1024, dl + 1024);
        }
        // compute current tile from LDS
        const char* Bp = &sm[(i & 1) * 8192 + lane * 16];
        float16 a;
#pragma unroll
        for (int reg = 0; reg < 16; ++reg) a[reg] = 0.f;
#pragma unroll
        for (int ks = 0; ks < 8; ++ks) {
            short8 Bf = *(const short8*)(Bp + ks * 1024);
            a = __builtin_amdgcn_mfma_f32_32x32x16_bf16(Ah[ks], Bf, a, 0, 0, 0);
        }
        epi_tile(a, cb, lcv[i], rnv[i], drv[i], isBatch && (cb == rb),
                 half, ln, growbase, rlab, sS, sN);
        __syncthreads();   // drains staged glds; next iter reads other buffer
    }

    const int slice = isB2 ? cg : (NCG2 + t1);
#pragma unroll
    for (int reg = 0; reg < 16; ++reg) {
        float av = sS[reg], c = sN[reg];
#pragma unroll
        for (int off = 1; off < 32; off <<= 1) {
            av += __shfl_xor(av, off, 64);
            c  += __shfl_xor(c, off, 64);
        }
        if (ln == 0) {
            int ro = (reg & 3) + 8 * (reg >> 2) + 4 * half;
            int grow = growbase + ro;
            pS[(size_t)slice * BB + grow] = av;
            pN[(size_t)slice * BB + grow] = c;
        }
    }
}

// ---------------- reduce: 128 blocks; 32 threads/row sum the 141 slices + loss math ----
__global__ __launch_bounds__(256) void reduce_k(
    const int* __restrict__ labels,
    const int* __restrict__ cntP, const int* __restrict__ cntB,
    const float* __restrict__ pS, const float* __restrict__ pN,
    const float* __restrict__ supS, const float* __restrict__ supLi,
    float* __restrict__ partial) {
    const int g = blockIdx.x, t = threadIdx.x;
    __shared__ float cA_s[128];
    __shared__ int   cB_s[128];
    if (t < 128) {
        int s = 0;
#pragma unroll
        for (int h = 0; h < NHIST; ++h) s += cntP[h * 128 + t];
        cA_s[t] = (float)s;
        cB_s[t] = cntB[t];
    }
    __syncthreads();
    const int rl = t >> 5, j = t & 31;        // 8 rows/block, 32 lanes/row
    const int row = g * 8 + rl;
    float S2 = 0.f, N2 = 0.f, S1 = 0.f, N1v = 0.f;
    for (int c = j; c < NCG2; c += 32) {
        S2 += pS[(size_t)c * BB + row];
        N2 += pN[(size_t)c * BB + row];
    }
    if (NCG2 + j < NSL) {
        S1  += pS[(size_t)(NCG2 + j) * BB + row];
        N1v += pN[(size_t)(NCG2 + j) * BB + row];
    }
#pragma unroll
    for (int off = 1; off < 32; off <<= 1) {
        S2 += __shfl_xor(S2, off, 64);  N2  += __shfl_xor(N2, off, 64);
        S1 += __shfl_xor(S1, off, 64);  N1v += __shfl_xor(N1v, off, 64);
    }
    float s = 0.f;
    if (j == 0) {
        int li = labels[row];
        S2 += supS[row];
        N2 *= INV_T; N1v *= INV_T;
        float sli = supLi[row];
        float cA = cA_s[li];
        float msum2 = fmaf(ALPHA, cA - 1.f, 1.f);
        float loss2 = -(fmaf(ALPHA, N2, sli) / msum2 - INV_T - logf(S2 + EPSV));
        float loss1 = -(N1v / (float)cB_s[li] - INV_T - logf(S1 + EPSV));
        s = loss1 + loss2;
    }
#pragma unroll
    for (int off = 1; off < 64; off <<= 1) s += __shfl_xor(s, off, 64);
    __shared__ float buf[4];
    if ((t & 63) == 0) buf[t >> 6] = s;
    __syncthreads();
    if (t == 0) partial[g] = (buf[0] + buf[1]) + (buf[2] + buf[3]);
}

// ---------------- final: one wave sums 128 block partials ----------------
__global__ __launch_bounds__(64) void final_k(const float* __restrict__ partial,
                                              float* __restrict__ out) {
    const int t = threadIdx.x;
    float s = partial[t] + partial[t + 64];
#pragma unroll
    for (int off = 1; off < 64; off <<= 1) s += __shfl_xor(s, off, 64);
    if (t == 0) out[0] = s / (float)BB;   // single writer, plain store
}

extern "C" void kernel_launch(void* const* d_in, const int* in_sizes, int n_in,
                              void* d_out, int out_size, void* d_ws, size_t ws_size,
                              hipStream_t stream) {
    const float* feats   = (const float*)d_in[0];
    const float* sup     = (const float*)d_in[1];
    const float* centers = (const float*)d_in[2];
    const int*   labels  = (const int*)d_in[3];
    float* out = (float*)d_out;
    char*  wsb = (char*)d_ws;

    const size_t X2_BYTES = (size_t)NCB * 8192;         // 8,683,520
    unsigned short* X2 = (unsigned short*)wsb;
    char* base2 = wsb + X2_BYTES;
    int* cntP = (int*)base2;                            // 33*128 ints
    int* cntB = cntP + NHIST * 128;                     // 128 ints
    float* pS = (float*)(cntB + 128);                   // 141*1024
    float* pN = pS + (size_t)NSL * BB;                  // 141*1024
    float* supS  = pN + (size_t)NSL * BB;               // 1024
    float* supLi = supS + BB;                           // 1024
    float* partial = supLi + BB;                        // 128

    // 4 nodes; every workspace word written before read (stream-ordered)
    prep_k<<<NCB + NHIST, 256, 0, stream>>>(feats, centers, labels, X2, cntP, cntB);
    gemm_k<<<18 * 64, 256, 0, stream>>>(X2, labels, cntP, cntB, sup,
                                        pS, pN, supS, supLi);
    reduce_k<<<128, 256, 0, stream>>>(labels, cntP, cntB, pS, pN, supS, supLi, partial);
    final_k<<<1, 64, 0, stream>>>(partial, out);
}

// Round 7
// 121.057 us; speedup vs baseline: 1.2703x; 1.0006x over previous
//
#include <hip/hip_runtime.h>
#include <math.h>

#define KQ   32768
#define CC   100
#define BB   1024
#define DD   128
#define NTOT (BB + KQ)        // 33792
#define CB_CENT 1056
#define NCB  1060             // 32-row blocks in X2
#define NPT  1088             // prep tile blocks (8 x 136, XCD-affine remap)
#define NHIST 33              // histogram partial blocks
#define NCG2 132              // branch-2 col groups (8 cb each)
#define CG_SUP 141            // sup group id (after 9 branch-1 groups)
#define NSL  141              // partial-sum slices (132 b2 + 9 b1)

#define INV_T  14.285714285714286f
#define K2E    20.609929f     // INV_T * log2(e)
#define ALPHA  0.05f
#define EPSV   1e-12f

typedef __attribute__((ext_vector_type(8)))  short          short8;
typedef __attribute__((ext_vector_type(8)))  unsigned short ushort8;
typedef __attribute__((ext_vector_type(16))) float          float16;

__device__ __forceinline__ unsigned short f2bf_rne(float f) {
    unsigned int u = __float_as_uint(f);
    return (unsigned short)((u + 0x7FFFu + ((u >> 16) & 1u)) >> 16);
}

// async global->LDS, 16B per lane: LDS dest = wave-uniform base + lane*16,
// global src is per-lane. Completion tracked by vmcnt; __syncthreads drains.
__device__ __forceinline__ void glds16(const void* g, void* l) {
    __builtin_amdgcn_global_load_lds(
        (const __attribute__((address_space(1))) void*)g,
        (__attribute__((address_space(3))) void*)l, 16, 0, 0);
}

// X2 layout per 32-row block cb (8192 B): [ks 0..7][lane 0..63][16 B]
// element (row r, k): cb=r>>5, ks=k>>4, lane=(r&31)+32*((k>>3)&1), j=k&7
// == 32x32x16 MFMA A/B operand layout (verified R2-R15).
// HARD RULES: no device-scope fences/tickets in hot kernel (R13);
// never plain-store into a cross-block atomic accumulation target (R14);
// gemm_k register demand must stay <= ~128 at 256-thread blocks:
//   R1: cap 64 -> 126 MB scratch spill; R5: 2-A-strip needs ~185 -> clamp
//   at 128 + spill (gemm 56->90us). Single 32-row A strip only.
// R0-R6: gemm wall ~56us invariant across 5 structures (reg-direct, LDS
// dbuf, hoisted gathers, glds); counters fit ~600MHz eff. clock with ~12K
// issue cycles vs ~35K wall -> stall is repeated long memory latency.
// R7 theory: prep wrote tile cb from XCD cb&7, gemm reads it from XCD
// (cb>>3)&7 -> every B read is a dirty-remote-L2 fabric round trip.
// Fix: XCD-affine prep remap so writer XCD == reader XCD.

// ---------------- prep: convert+tile (XCD-affine cb remap) + partial histograms -------
__global__ __launch_bounds__(256) void prep_k(const float* __restrict__ feats,
                                              const float* __restrict__ centers,
                                              const int* __restrict__ labels,
                                              unsigned short* __restrict__ X2,
                                              int* __restrict__ cntP,
                                              int* __restrict__ cntB) {
    const int b = blockIdx.x, t = threadIdx.x;
    if (b >= NPT) {  // histogram partials: each block owns its own 128-int slice
        const int h = b - NPT;
        __shared__ int hA[CC], hB[CC];
        if (t < CC) { hA[t] = 0; hB[t] = 0; }
        __syncthreads();
        const int base = h * 1024;
#pragma unroll
        for (int q = 0; q < 4; ++q) {
            int l = labels[base + q * 256 + t];
            atomicAdd(&hA[l], 1);
            if (h == 0) atomicAdd(&hB[l], 1);   // batch rows are exactly block 0's range
        }
        __syncthreads();
        if (t < 128) {
            cntP[h * 128 + t] = (t < CC) ? hA[t] : 0;
            if (h == 0) cntB[t] = (t < CC) ? hB[t] : 0;
        }
        return;
    }
    // XCD-affine remap: block with x=b&7 writes exactly the tiles gemm's
    // XCD x reads: cb = cg*8 + k with cg = x + 8*(i>>3), k = i&7.
    const int x = b & 7, i = b >> 3;
    const int cg_ = x + 8 * (i >> 3);
    const int cb = cg_ * 8 + (i & 7);
    if (cb >= NCB) return;               // 28 pad blocks idle
    __shared__ unsigned short sm[8 * 66 * 8];   // stride-66 slots
    const int rl = t >> 3, c8 = t & 7;
    const int r = cb * 32 + rl;
    const float* src;
    if (r < NTOT)            src = &feats[(size_t)r * DD];
    else if (r < NTOT + CC)  src = &centers[(size_t)(r - NTOT) * DD];
    else                     src = nullptr;
#pragma unroll
    for (int s = 0; s < 2; ++s) {
        const int c8p = c8 + 8 * s;
        float v[8];
        if (src) {
            const float4* p = (const float4*)(src + c8p * 8);
            float4 q0 = p[0], q1 = p[1];
            v[0]=q0.x; v[1]=q0.y; v[2]=q0.z; v[3]=q0.w;
            v[4]=q1.x; v[5]=q1.y; v[6]=q1.z; v[7]=q1.w;
        } else {
#pragma unroll
            for (int j = 0; j < 8; ++j) v[j] = 0.f;
        }
        ushort8 H;
#pragma unroll
        for (int m = 0; m < 8; ++m) H[m] = f2bf_rne(v[m]);
        const int ks = c8p >> 1, lh = c8p & 1;
        *(ushort8*)&sm[(ks * 66 + rl + 32 * lh) * 8] = H;
    }
    __syncthreads();
    ushort8* dst = (ushort8*)((char*)X2 + (size_t)cb * 8192);
#pragma unroll
    for (int j = 0; j < 2; ++j) {
        const int idx = j * 256 + t;
        const int ks = idx >> 6, ln2 = idx & 63;
        dst[idx] = *(const ushort8*)&sm[(ks * 66 + ln2) * 8];
    }
}

// ---------------- epilogue for one 32x32 tile ----------------
__device__ __forceinline__ void epi_tile(
    const float16& acc, int cb, int lc, float rn, float drm, bool checkDiag,
    int half, int ln, int growbase, const int* rlab, float* sS, float* sN)
{
    const int ccol = cb * 32 + ln;
#pragma unroll
    for (int reg = 0; reg < 16; ++reg) {
        int ro = (reg & 3) + 8 * (reg >> 2) + 4 * half;
        float a  = acc[reg];
        float mf = (lc == rlab[reg]) ? 1.f : 0.f;
        float wgt = fmaf(mf, drm, rn);
        if (checkDiag) {                 // wave-uniform
            bool d = (ccol == growbase + ro);
            wgt = d ? 0.f : wgt;
            mf  = d ? 0.f : mf;
        }
        float e = exp2f(fmaf(a, K2E, -K2E));
        sS[reg] = fmaf(e, wgt, sS[reg]);
        sN[reg] = fmaf(mf, a, sN[reg]);  // un-scaled dot; *INV_T at finalize
    }
}

// ---------------- fused GEMM (b2 + b1) + sup-sums; 4-wave, glds double-buffer ----------
// grid 1152 = 18 chunk * 8 rgrp * 8 xcd; cg = chunk*8 + xcd.
// cg<132: branch2 (8 cb). 132..140: branch1 (4 cb). 141: sup sums. 142/143: idle.
// B tiles are L2-local: prep wrote them from the same XCD (R7 remap).
__global__ __launch_bounds__(256, 2) void gemm_k(
    const unsigned short* __restrict__ X2, const int* __restrict__ labels,
    const int* __restrict__ cntP, const int* __restrict__ cntB,
    const float* __restrict__ sup,
    float* __restrict__ pS, float* __restrict__ pN,
    float* __restrict__ supS, float* __restrict__ supLi) {
    const int b = blockIdx.x;
    const int xcd = b & 7, rgrp = (b >> 3) & 7, chunk = b >> 6;
    const int cg = chunk * 8 + xcd;
    if (cg > CG_SUP) return;

    const int tid = threadIdx.x;
    const int w = tid >> 6, lane = tid & 63;
    const int half = lane >> 5, ln = lane & 31;
    const int rb = rgrp * 4 + w;
    const char* Xb = (const char*)X2;

    if (cg == CG_SUP) {  // sup-logits exp-sums: wave owns rows rb*32..rb*32+31
        const int c0 = lane, c1 = lane + 64;
        int s0 = 0, s1 = 0;
#pragma unroll
        for (int h = 0; h < NHIST; ++h) {
            s0 += cntP[h * 128 + c0];
            s1 += cntP[h * 128 + c1];
        }
        float n0 = (float)s0;
        float rA0 = __builtin_amdgcn_rcpf(n0);
        float rAm0 = __builtin_amdgcn_rcpf(fmaxf(n0 - 1.f, 1.f));
        float rA1 = 0.f, rAm1 = 0.f;
        if (lane < 36) {
            float n1 = (float)s1;
            rA1 = __builtin_amdgcn_rcpf(n1);
            rAm1 = __builtin_amdgcn_rcpf(fmaxf(n1 - 1.f, 1.f));
        }
        for (int rr = 0; rr < 32; ++rr) {
            int row = rb * 32 + rr;
            int li = labels[row];
            const float* srow = &sup[(size_t)row * CC];
            float v0 = srow[c0];
            float s = __expf(v0 - INV_T) * ((c0 == li) ? rAm0 : rA0);
            float liv = (c0 == li) ? v0 : 0.f;
            if (lane < 36) {
                float v1 = srow[c1];
                s += __expf(v1 - INV_T) * ((c1 == li) ? rAm1 : rA1);
                liv += (c1 == li) ? v1 : 0.f;
            }
#pragma unroll
            for (int off = 1; off < 64; off <<= 1) {
                s += __shfl_xor(s, off, 64);
                liv += __shfl_xor(liv, off, 64);
            }
            if (lane == 0) { supS[row] = s; supLi[row] = liv; }
        }
        return;
    }

    __shared__ char sm[2 * 8192];       // double-buffered B tile (MFMA operand order)
    __shared__ float2 wT[128];          // in-block weight table

    const bool isB2 = (cg < NCG2);
    const int t1 = cg - NCG2;
    const bool isBatch = isB2 || (t1 < 8);
    const int NIT = isB2 ? 8 : 4;
    const int cb0 = isB2 ? cg * 8 : (t1 < 8 ? t1 * 4 : CB_CENT);

    // in-block weight table from histogram partials (exact tables_k expressions)
    if (tid < 128) {
        int s = 0;
#pragma unroll
        for (int h = 0; h < NHIST; ++h) s += cntP[h * 128 + tid];
        float2 wv;
        if (isB2) {
            float cf = (float)s;
            float rn = (s > 0) ? __builtin_amdgcn_rcpf(cf) : 0.f;
            wv = make_float2(rn, (s > 0) ? (__builtin_amdgcn_rcpf(cf - ALPHA) - rn) : 0.f);
        } else {
            float c1 = (float)(cntB[tid] + 1);
            float r1 = __builtin_amdgcn_rcpf(c1);
            wv = make_float2(r1, __builtin_amdgcn_rcpf(fmaxf(c1 - 1.f, 1.f)) - r1);
        }
        wT[tid] = wv;
    }

    // prologue: async-stage cb0 into buffer 0 (wave w owns 2 KB slice)
    const int wbase = w * 2048;
    {
        const char* src = Xb + (size_t)cb0 * 8192 + wbase + lane * 16;
        glds16(src, &sm[wbase]);
        glds16(src + 1024, &sm[wbase + 1024]);
    }

    // ---- hoisted per-tile column labels (independent global gathers) ----
    int lcv[8];
#pragma unroll
    for (int i = 0; i < 8; ++i) {
        if (i < NIT) {
            const int cb = cb0 + i;
            if (isBatch) {
                lcv[i] = labels[cb * 32 + ln];
            } else {
                int q = cb * 32 + ln - NTOT;
                lcv[i] = (q < CC) ? q : -1;
            }
        } else lcv[i] = -1;
    }

    const int growbase = rb * 32;
    short8 Ah[8];
    {
        size_t abase = (size_t)rb * 8192 + (size_t)lane * 16;
#pragma unroll
        for (int ks = 0; ks < 8; ++ks)
            Ah[ks] = *(const short8*)(Xb + abase + (size_t)ks * 1024);
    }
    int rlab[16];
#pragma unroll
    for (int reg = 0; reg < 16; ++reg) {
        int ro = (reg & 3) + 8 * (reg >> 2) + 4 * half;
        rlab[reg] = labels[growbase + ro];
    }

    __syncthreads();   // wT visible + buffer-0 staging drained (vmcnt)

    // ---- hoisted per-tile weights from LDS table ----
    float rnv[8], drv[8];
#pragma unroll
    for (int i = 0; i < 8; ++i) {
        if (i < NIT) {
            int lc = lcv[i];
            float2 wv = wT[(lc >= 0) ? lc : 0];
            rnv[i] = (lc >= 0) ? wv.x : 0.f;
            drv[i] = (lc >= 0) ? wv.y : 0.f;
        } else { rnv[i] = 0.f; drv[i] = 0.f; }
    }

    float sS[16], sN[16];
#pragma unroll
    for (int reg = 0; reg < 16; ++reg) { sS[reg] = 0.f; sN[reg] = 0.f; }

    for (int i = 0; i < NIT; ++i) {
        const int cb = cb0 + i;
        const bool more = (i + 1 < NIT);
        // async-issue next tile's staging into the other buffer
        if (more) {
            const char* src = Xb + (size_t)(cb + 1) * 8192 + wbase + lane * 16;
            char* dl = &sm[((i + 1) & 1) * 8192 + wbase];
            glds16(src, dl);
            glds16(src + 1024, dl + 1024);
        }
        // compute current tile from LDS
        const char* Bp = &sm[(i & 1) * 8192 + lane * 16];
        float16 a;
#pragma unroll
        for (int reg = 0; reg < 16; ++reg) a[reg] = 0.f;
#pragma unroll
        for (int ks = 0; ks < 8; ++ks) {
            short8 Bf = *(const short8*)(Bp + ks * 1024);
            a = __builtin_amdgcn_mfma_f32_32x32x16_bf16(Ah[ks], Bf, a, 0, 0, 0);
        }
        epi_tile(a, cb, lcv[i], rnv[i], drv[i], isBatch && (cb == rb),
                 half, ln, growbase, rlab, sS, sN);
        __syncthreads();   // drains staged glds; next iter reads other buffer
    }

    const int slice = isB2 ? cg : (NCG2 + t1);
#pragma unroll
    for (int reg = 0; reg < 16; ++reg) {
        float av = sS[reg], c = sN[reg];
#pragma unroll
        for (int off = 1; off < 32; off <<= 1) {
            av += __shfl_xor(av, off, 64);
            c  += __shfl_xor(c, off, 64);
        }
        if (ln == 0) {
            int ro = (reg & 3) + 8 * (reg >> 2) + 4 * half;
            int grow = growbase + ro;
            pS[(size_t)slice * BB + grow] = av;
            pN[(size_t)slice * BB + grow] = c;
        }
    }
}

// ---------------- reduce: 128 blocks; 32 threads/row sum the 141 slices + loss math ----
__global__ __launch_bounds__(256) void reduce_k(
    const int* __restrict__ labels,
    const int* __restrict__ cntP, const int* __restrict__ cntB,
    const float* __restrict__ pS, const float* __restrict__ pN,
    const float* __restrict__ supS, const float* __restrict__ supLi,
    float* __restrict__ partial) {
    const int g = blockIdx.x, t = threadIdx.x;
    __shared__ float cA_s[128];
    __shared__ int   cB_s[128];
    if (t < 128) {
        int s = 0;
#pragma unroll
        for (int h = 0; h < NHIST; ++h) s += cntP[h * 128 + t];
        cA_s[t] = (float)s;
        cB_s[t] = cntB[t];
    }
    __syncthreads();
    const int rl = t >> 5, j = t & 31;        // 8 rows/block, 32 lanes/row
    const int row = g * 8 + rl;
    float S2 = 0.f, N2 = 0.f, S1 = 0.f, N1v = 0.f;
    for (int c = j; c < NCG2; c += 32) {
        S2 += pS[(size_t)c * BB + row];
        N2 += pN[(size_t)c * BB + row];
    }
    if (NCG2 + j < NSL) {
        S1  += pS[(size_t)(NCG2 + j) * BB + row];
        N1v += pN[(size_t)(NCG2 + j) * BB + row];
    }
#pragma unroll
    for (int off = 1; off < 32; off <<= 1) {
        S2 += __shfl_xor(S2, off, 64);  N2  += __shfl_xor(N2, off, 64);
        S1 += __shfl_xor(S1, off, 64);  N1v += __shfl_xor(N1v, off, 64);
    }
    float s = 0.f;
    if (j == 0) {
        int li = labels[row];
        S2 += supS[row];
        N2 *= INV_T; N1v *= INV_T;
        float sli = supLi[row];
        float cA = cA_s[li];
        float msum2 = fmaf(ALPHA, cA - 1.f, 1.f);
        float loss2 = -(fmaf(ALPHA, N2, sli) / msum2 - INV_T - logf(S2 + EPSV));
        float loss1 = -(N1v / (float)cB_s[li] - INV_T - logf(S1 + EPSV));
        s = loss1 + loss2;
    }
#pragma unroll
    for (int off = 1; off < 64; off <<= 1) s += __shfl_xor(s, off, 64);
    __shared__ float buf[4];
    if ((t & 63) == 0) buf[t >> 6] = s;
    __syncthreads();
    if (t == 0) partial[g] = (buf[0] + buf[1]) + (buf[2] + buf[3]);
}

// ---------------- final: one wave sums 128 block partials ----------------
__global__ __launch_bounds__(64) void final_k(const float* __restrict__ partial,
                                              float* __restrict__ out) {
    const int t = threadIdx.x;
    float s = partial[t] + partial[t + 64];
#pragma unroll
    for (int off = 1; off < 64; off <<= 1) s += __shfl_xor(s, off, 64);
    if (t == 0) out[0] = s / (float)BB;   // single writer, plain store
}

extern "C" void kernel_launch(void* const* d_in, const int* in_sizes, int n_in,
                              void* d_out, int out_size, void* d_ws, size_t ws_size,
                              hipStream_t stream) {
    const float* feats   = (const float*)d_in[0];
    const float* sup     = (const float*)d_in[1];
    const float* centers = (const float*)d_in[2];
    const int*   labels  = (const int*)d_in[3];
    float* out = (float*)d_out;
    char*  wsb = (char*)d_ws;

    const size_t X2_BYTES = (size_t)NCB * 8192;         // 8,683,520
    unsigned short* X2 = (unsigned short*)wsb;
    char* base2 = wsb + X2_BYTES;
    int* cntP = (int*)base2;                            // 33*128 ints
    int* cntB = cntP + NHIST * 128;                     // 128 ints
    float* pS = (float*)(cntB + 128);                   // 141*1024
    float* pN = pS + (size_t)NSL * BB;                  // 141*1024
    float* supS  = pN + (size_t)NSL * BB;               // 1024
    float* supLi = supS + BB;                           // 1024
    float* partial = supLi + BB;                        // 128

    // 4 nodes; every workspace word written before read (stream-ordered)
    prep_k<<<NPT + NHIST, 256, 0, stream>>>(feats, centers, labels, X2, cntP, cntB);
    gemm_k<<<18 * 64, 256, 0, stream>>>(X2, labels, cntP, cntB, sup,
                                        pS, pN, supS, supLi);
    reduce_k<<<128, 256, 0, stream>>>(labels, cntP, cntB, pS, pN, supS, supLi, partial);
    final_k<<<1, 64, 0, stream>>>(partial, out);
}